// Round 8
// baseline (207.606 us; speedup 1.0000x reference)
//
#include <hip/hip_runtime.h>
#include <hip/hip_bf16.h>
#include <cstdint>
#include <cstddef>

// GAT layer forward for MI355X (gfx950).
// N=50000, E=1.6M, F=256, H=64 (derived at runtime).
// Outputs (concat in d_out): out [N,H] f32, alpha [E] f32.

constexpr int FDIM = 256;
constexpr int HDIM = 64;
constexpr float LEAKY = 0.05f;
constexpr int LH_CAP = 25088;             // u32 capacity: supports N <= 50176

typedef __attribute__((ext_vector_type(8))) short short8v;   // 8 bf16 = 4 VGPR
typedef __attribute__((ext_vector_type(4))) float f32x4;

__device__ __forceinline__ short bfs(float f) {
  return (short)__builtin_bit_cast(unsigned short, __float2bfloat16(f));
}
__device__ __forceinline__ short8v cvt8(float4 lo, float4 hi) {
  short8v r;
  r[0] = bfs(lo.x); r[1] = bfs(lo.y); r[2] = bfs(lo.z); r[3] = bfs(lo.w);
  r[4] = bfs(hi.x); r[5] = bfs(hi.y); r[6] = bfs(hi.z); r[7] = bfs(hi.w);
  return r;
}

// ---------------------------------------------------------------------------
// K0: pack fc_w (f32 [64][256]) into bf16 MFMA B-fragments.
// ---------------------------------------------------------------------------
__global__ __launch_bounds__(256) void k_wt(
    const float* __restrict__ fcw, short* __restrict__ wb)
{
  const int t = blockIdx.x * 256 + threadIdx.x;   // 0 .. 2047
  const int f = t >> 6;
  const int lane = t & 63;
  const int ks = f >> 2, cb = f & 3;
  const int col = cb * 16 + (lane & 15);
  const int kb = ks * 32 + (lane >> 4) * 8;
  short8v v;
  #pragma unroll
  for (int j = 0; j < 8; ++j) v[j] = bfs(fcw[col * FDIM + kb + j]);
  reinterpret_cast<short8v*>(wb)[t] = v;
}

// ---------------------------------------------------------------------------
// K1: MFMA GEMM z = x @ fc_w^T (bf16 in, f32 acc), fused s1/s2, z out bf16.
// C/D layout (verified): col = lane&15, row = (lane>>4)*4 + reg.
// ---------------------------------------------------------------------------
__global__ __launch_bounds__(256) void k_fcm(
    const float* __restrict__ x, const short* __restrict__ wb,
    const float* __restrict__ aw,
    unsigned short* __restrict__ zb, float* __restrict__ s1,
    float* __restrict__ s2, int N)
{
  __shared__ __align__(16) unsigned short zt[128 * 72];   // 18.4 KB transpose buf

  const int tid = threadIdx.x;
  const int lane = tid & 63;
  const int wave = tid >> 6;
  const int n0 = blockIdx.x * 128;
  const int rb = n0 + wave * 32;
  const int l4 = lane >> 4;      // k-group / row-group
  const int lm = lane & 15;      // A-row / B-col within tile

  f32x4 acc[2][4] = {};

  const int r0c = min(rb + lm, N - 1);
  const int r1c = min(rb + 16 + lm, N - 1);
  const float* xp0 = x + (size_t)r0c * FDIM + l4 * 8;
  const float* xp1 = x + (size_t)r1c * FDIM + l4 * 8;
  const short8v* wbv = reinterpret_cast<const short8v*>(wb);

  #pragma unroll
  for (int ks = 0; ks < 8; ++ks) {
    const float4 a0l = *reinterpret_cast<const float4*>(xp0 + ks * 32);
    const float4 a0h = *reinterpret_cast<const float4*>(xp0 + ks * 32 + 4);
    const float4 a1l = *reinterpret_cast<const float4*>(xp1 + ks * 32);
    const float4 a1h = *reinterpret_cast<const float4*>(xp1 + ks * 32 + 4);
    const short8v fa0 = cvt8(a0l, a0h);
    const short8v fa1 = cvt8(a1l, a1h);
    #pragma unroll
    for (int cb = 0; cb < 4; ++cb) {
      const short8v fb = wbv[(ks * 4 + cb) * 64 + lane];
      acc[0][cb] = __builtin_amdgcn_mfma_f32_16x16x32_bf16(fa0, fb, acc[0][cb], 0, 0, 0);
      acc[1][cb] = __builtin_amdgcn_mfma_f32_16x16x32_bf16(fa1, fb, acc[1][cb], 0, 0, 0);
    }
  }

  // fused s1/s2
  float aw1l[4], aw2l[4];
  #pragma unroll
  for (int cb = 0; cb < 4; ++cb) {
    aw1l[cb] = aw[cb * 16 + lm];
    aw2l[cb] = aw[HDIM + cb * 16 + lm];
  }
  #pragma unroll
  for (int mb = 0; mb < 2; ++mb) {
    const int rloc = rb + mb * 16 + l4 * 4;
    #pragma unroll
    for (int reg = 0; reg < 4; ++reg) {
      float t1 = 0.f, t2 = 0.f;
      #pragma unroll
      for (int cb = 0; cb < 4; ++cb) {
        t1 = fmaf(acc[mb][cb][reg], aw1l[cb], t1);
        t2 = fmaf(acc[mb][cb][reg], aw2l[cb], t2);
      }
      #pragma unroll
      for (int off = 1; off < 16; off <<= 1) {
        t1 += __shfl_xor(t1, off, 64);
        t2 += __shfl_xor(t2, off, 64);
      }
      if (lm == reg && rloc + reg < N) {
        s1[rloc + reg] = t1;
        s2[rloc + reg] = t2;
      }
    }
  }

  // z -> bf16 via LDS transpose, then coalesced stores (64B per thread)
  #pragma unroll
  for (int mb = 0; mb < 2; ++mb)
    #pragma unroll
    for (int cb = 0; cb < 4; ++cb)
      #pragma unroll
      for (int reg = 0; reg < 4; ++reg) {
        const int rl = wave * 32 + mb * 16 + l4 * 4 + reg;
        zt[rl * 72 + cb * 16 + lm] =
            (unsigned short)__builtin_bit_cast(unsigned short,
                __float2bfloat16(acc[mb][cb][reg]));
      }
  __syncthreads();
  const int row = tid >> 1, hf = tid & 1;   // 32 u16 = 64 B = 4 x uint4 each
  const int n = n0 + row;
  if (n < N) {
    const uint4* s = reinterpret_cast<const uint4*>(&zt[row * 72 + hf * 32]);
    uint4 v0 = s[0], v1 = s[1], v2 = s[2], v3 = s[3];
    uint4* d = reinterpret_cast<uint4*>(zb + (size_t)n * HDIM + hf * 32);
    d[0] = v0; d[1] = v1; d[2] = v2; d[3] = v3;
  }
}

// ---------------------------------------------------------------------------
// K2: LDS-privatized histogram. One block per (1<<chunkLg)-edge chunk.
// Counts packed 2 x u16 per u32 (safe: per-node degree << 65536).
// Emits per-edge within-block rank (lrank) + per-block histogram row.
// ---------------------------------------------------------------------------
__global__ __launch_bounds__(1024) void k_histL(
    const int* __restrict__ src, unsigned int* __restrict__ hist,
    unsigned short* __restrict__ lrank, int E, int nCol, int chunkLg)
{
  __shared__ unsigned int lh[LH_CAP];     // 100 KB
  const int tid = threadIdx.x;
  for (int i = tid; i < nCol; i += 1024) lh[i] = 0;
  __syncthreads();
  const int e0 = blockIdx.x << chunkLg;
  const int e1 = min(e0 + (1 << chunkLg), E);
  for (int e = e0 + tid; e < e1; e += 1024) {
    const int s = src[e];
    const int sh = (s & 1) * 16;
    const unsigned int old = atomicAdd(&lh[s >> 1], 1u << sh);
    lrank[e] = (unsigned short)((old >> sh) & 0xffffu);
  }
  __syncthreads();
  unsigned int* hrow = hist + (size_t)blockIdx.x * nCol;
  for (int i = tid; i < nCol; i += 1024) hrow[i] = lh[i];
}

// ---------------------------------------------------------------------------
// K2b: column scan over blocks (in-place: hist row b becomes exclusive base
// for block b), plus total counts cnt[n].
// ---------------------------------------------------------------------------
__global__ __launch_bounds__(256) void k_colscan(
    unsigned int* __restrict__ hist, int* __restrict__ cnt,
    int nCol, int B, int N)
{
  const int c = blockIdx.x * 256 + threadIdx.x;
  if (c >= nCol) return;
  unsigned int s0 = 0, s1 = 0;
  for (int b = 0; b < B; ++b) {
    unsigned int* p = hist + (size_t)b * nCol + c;
    const unsigned int v = *p;
    *p = s0 | (s1 << 16);
    s0 += v & 0xffffu;
    s1 += v >> 16;
  }
  const int n0 = 2 * c;
  if (n0 < N) cnt[n0] = (int)s0;
  if (n0 + 1 < N) cnt[n0 + 1] = (int)s1;
}

// ---------------------------------------------------------------------------
// K3a: per-block exclusive scan (1024/block) + block sums
// ---------------------------------------------------------------------------
__global__ __launch_bounds__(1024) void k_scan1(
    const int* __restrict__ cnt, int* __restrict__ rowptr,
    int* __restrict__ bsum, int N)
{
  __shared__ int wsum[16];
  const int i = blockIdx.x * 1024 + threadIdx.x;
  const int lane = threadIdx.x & 63;
  const int wave = threadIdx.x >> 6;
  const int v = (i < N) ? cnt[i] : 0;
  int s = v;
  #pragma unroll
  for (int off = 1; off < 64; off <<= 1) {
    int t = __shfl_up(s, off, 64);
    if (lane >= off) s += t;
  }
  if (lane == 63) wsum[wave] = s;
  __syncthreads();
  if (threadIdx.x < 16) {
    int w = wsum[threadIdx.x];
    #pragma unroll
    for (int off = 1; off < 16; off <<= 1) {
      int t = __shfl_up(w, off, 64);
      if (threadIdx.x >= off) w += t;
    }
    wsum[threadIdx.x] = w;   // inclusive across waves
  }
  __syncthreads();
  const int base = (wave > 0) ? wsum[wave - 1] : 0;
  if (i < N) rowptr[i] = base + s - v;      // block-local exclusive
  if (threadIdx.x == 0) bsum[blockIdx.x] = wsum[15];
}

// ---------------------------------------------------------------------------
// K3b: single-block exclusive scan of block sums (B <= 1024)
// ---------------------------------------------------------------------------
__global__ __launch_bounds__(1024) void k_scan2(int* __restrict__ bsum, int B)
{
  __shared__ int part[1024];
  const int t = threadIdx.x;
  const int v = (t < B) ? bsum[t] : 0;
  part[t] = v;
  __syncthreads();
  for (int off = 1; off < 1024; off <<= 1) {
    int u = (t >= off) ? part[t - off] : 0;
    __syncthreads();
    part[t] += u;
    __syncthreads();
  }
  if (t < B) bsum[t] = part[t] - v;   // exclusive
}

// ---------------------------------------------------------------------------
// K3c: add block offsets; set rowptr[N] = E
// ---------------------------------------------------------------------------
__global__ __launch_bounds__(1024) void k_scan3(
    int* __restrict__ rowptr, const int* __restrict__ bsum, int N, int E)
{
  const int i = blockIdx.x * 1024 + threadIdx.x;
  if (i < N) rowptr[i] += bsum[blockIdx.x];
  if (i == 0) rowptr[N] = E;
}

// ---------------------------------------------------------------------------
// K4: atomic-free CSR placement:
// pos = rowptr[src] + colbase[e>>chunkLg][src] + lrank[e]
// ---------------------------------------------------------------------------
__global__ __launch_bounds__(256) void k_place(
    const int* __restrict__ src, const int* __restrict__ dst,
    const int* __restrict__ rowptr, const unsigned int* __restrict__ colbase,
    const unsigned short* __restrict__ lrank,
    unsigned short* __restrict__ csr_dst, int E, int nCol, int chunkLg)
{
  int e = blockIdx.x * 256 + threadIdx.x;
  if (e >= E) return;
  const int s = src[e];
  const unsigned int cb = colbase[(size_t)(e >> chunkLg) * nCol + (s >> 1)];
  const int base = (int)((cb >> ((s & 1) * 16)) & 0xffffu);
  csr_dst[rowptr[s] + base + (int)lrank[e]] = (unsigned short)dst[e];
}

// ---------------------------------------------------------------------------
// K5: node-centric accumulate; wave/node; 2 edges per iteration; unroll 8
// keeps ~8 independent 256B gathers in flight (latency-bound otherwise).
// ---------------------------------------------------------------------------
__global__ __launch_bounds__(256) void k_node(
    const unsigned short* __restrict__ csr_dst, const int* __restrict__ rowptr,
    const float* __restrict__ s1, const float* __restrict__ s2,
    const float* __restrict__ ab, const unsigned short* __restrict__ zb,
    float* __restrict__ out, float* __restrict__ rinv, int N)
{
  const int node = blockIdx.x * 4 + (threadIdx.x >> 6);
  const int lane = threadIdx.x & 63;
  if (node >= N) return;
  const int r0 = rowptr[node];
  const int r1 = rowptr[node + 1];
  if (r1 == r0) {            // degree-0: reference yields zeros
    out[(size_t)node * HDIM + lane] = 0.f;
    if (lane == 0) rinv[node] = 0.f;
    return;
  }
  const float s1n = s1[node];
  const float b = ab[0];
  const int half = lane >> 5;
  const int fp = (lane & 31) << 1;   // feature pair base
  float ax = 0.f, ay = 0.f, hs = 0.f;

  for (int base = r0; base < r1; base += 64) {
    const int j = base + lane;
    float h = 0.f;
    int dl = 0;
    if (j < r1) {
      dl = (int)csr_dst[j];                  // coalesced u16
      float v = s1n + s2[dl] + b;            // gathered 4B (L2-resident)
      v = v > 0.f ? v : LEAKY * v;
      h = __expf(v);
    }
    hs += h;
    const int cnt = min(64, r1 - base);
    const int pairs = (cnt + 1) >> 1;
    #pragma unroll 8
    for (int t = 0; t < pairs; ++t) {
      const int sl = 2 * t + half;           // lanes beyond cnt carry h=0
      const float hB = __shfl(h, sl, 64);
      const int dB = __shfl(dl, sl, 64);
      const unsigned int w = *reinterpret_cast<const unsigned int*>(
          zb + (size_t)dB * HDIM + fp);
      const float z0 = __uint_as_float(w << 16);
      const float z1 = __uint_as_float(w & 0xffff0000u);
      ax = fmaf(hB, z0, ax);
      ay = fmaf(hB, z1, ay);
    }
  }
  #pragma unroll
  for (int off = 32; off > 0; off >>= 1) hs += __shfl_xor(hs, off, 64);
  // combine even/odd halves (same feature pair lives at lane^32)
  ax += __shfl_xor(ax, 32, 64);
  ay += __shfl_xor(ay, 32, 64);
  const float inv = 1.0f / hs;
  if (lane < 32) {
    float2 o = {ax * inv, ay * inv};
    *reinterpret_cast<float2*>(out + (size_t)node * HDIM + fp) = o;
    if (lane == 0) rinv[node] = inv;
  }
}

// ---------------------------------------------------------------------------
// K6: alpha in edge order (coalesced writes)
// ---------------------------------------------------------------------------
__global__ __launch_bounds__(256) void k_alpha(
    const int* __restrict__ src, const int* __restrict__ dst,
    const float* __restrict__ s1, const float* __restrict__ s2,
    const float* __restrict__ ab, const float* __restrict__ rinv,
    float* __restrict__ alpha, int E)
{
  int e = blockIdx.x * blockDim.x + threadIdx.x;
  if (e >= E) return;
  const int s = src[e];
  float v = s1[s] + s2[dst[e]] + ab[0];
  v = v > 0.f ? v : LEAKY * v;
  alpha[e] = __expf(v) * rinv[s];
}

extern "C" void kernel_launch(void* const* d_in, const int* in_sizes, int n_in,
                              void* d_out, int out_size, void* d_ws, size_t ws_size,
                              hipStream_t stream) {
  const int E  = in_sizes[1] / 2;
  const int H2 = in_sizes[3];            // 2*H = 128
  const int Hh = H2 / 2;                 // 64
  const int Ff = in_sizes[2] / Hh;       // 256
  const int N  = in_sizes[0] / Ff;       // 50000

  const float* x   = (const float*)d_in[0];
  const int*   ei  = (const int*)d_in[1];
  const float* fcw = (const float*)d_in[2];
  const float* aw  = (const float*)d_in[3];
  const float* ab  = (const float*)d_in[4];
  const int* src = ei;
  const int* dst = ei + E;

  float* out   = (float*)d_out;
  float* alpha = out + (size_t)N * HDIM;

  const int nCol = (N + 1) / 2;                       // packed u16-pair columns

  // workspace layout:
  // zb u16[N*64] | s1 f32[N] | s2 f32[N] | rinv f32[N] | wb s16[16384]
  // | cnt i32[N] | rowptr i32[N+1] | bsum i32[1024] | lrank u16[E]
  // | csr_dst u16[E] | hist u32[nbH*nCol]
  unsigned short* zb = (unsigned short*)d_ws;
  float* s1   = (float*)(zb + (size_t)N * HDIM);
  float* s2   = s1 + N;
  float* rinv = s2 + N;
  short* wb   = (short*)(rinv + N);
  int* cnt    = (int*)(wb + 8 * 4 * 64 * 8);
  int* rowptr = cnt + N;
  int* bsum   = rowptr + (N + 1);
  unsigned short* lrank   = (unsigned short*)(bsum + 1024);
  unsigned short* csr_dst = lrank + E;
  unsigned int* hist = (unsigned int*)(csr_dst + ((E + 1) & ~1));

  // choose smallest chunk (most histogram parallelism) whose hist fits d_ws
  const size_t fixed_bytes = (size_t)((char*)hist - (char*)d_ws);
  int chunkLg = 13;
  while (chunkLg < 21) {
    const size_t nbH_t = ((size_t)E + ((size_t)1 << chunkLg) - 1) >> chunkLg;
    if (fixed_bytes + nbH_t * (size_t)nCol * 4 <= ws_size) break;
    ++chunkLg;
  }
  const int nbH = (int)(((size_t)E + ((size_t)1 << chunkLg) - 1) >> chunkLg);

  k_wt<<<8, 256, 0, stream>>>(fcw, wb);
  k_fcm<<<(N + 127) / 128, 256, 0, stream>>>(x, wb, aw, zb, s1, s2, N);

  k_histL<<<nbH, 1024, 0, stream>>>(src, hist, lrank, E, nCol, chunkLg);
  k_colscan<<<(nCol + 255) / 256, 256, 0, stream>>>(hist, cnt, nCol, nbH, N);

  const int nb1 = (N + 1023) / 1024;
  k_scan1<<<nb1, 1024, 0, stream>>>(cnt, rowptr, bsum, N);
  k_scan2<<<1, 1024, 0, stream>>>(bsum, nb1);
  k_scan3<<<nb1, 1024, 0, stream>>>(rowptr, bsum, N, E);

  const int eb = (E + 255) / 256;
  k_place<<<eb, 256, 0, stream>>>(src, dst, rowptr, hist, lrank, csr_dst,
                                  E, nCol, chunkLg);

  k_node<<<(N + 3) / 4, 256, 0, stream>>>(
      csr_dst, rowptr, s1, s2, ab, zb, out, rinv, N);

  k_alpha<<<eb, 256, 0, stream>>>(src, dst, s1, s2, ab, rinv, alpha, E);
}

// Round 9
// 140.492 us; speedup vs baseline: 1.4777x; 1.4777x over previous
//
#include <hip/hip_runtime.h>
#include <hip/hip_bf16.h>
#include <cstdint>
#include <cstddef>

// GAT layer forward for MI355X (gfx950).
// N=50000, E=1.6M, F=256, H=64 (derived at runtime).
// Outputs (concat in d_out): out [N,H] f32, alpha [E] f32.

constexpr int FDIM = 256;
constexpr int HDIM = 64;
constexpr float LEAKY = 0.05f;
constexpr int LH_CAP = 25088;             // u32 capacity: supports N <= 50176

typedef __attribute__((ext_vector_type(8))) short short8v;   // 8 bf16 = 4 VGPR
typedef __attribute__((ext_vector_type(4))) float f32x4;

__device__ __forceinline__ short bfs(float f) {
  return (short)__builtin_bit_cast(unsigned short, __float2bfloat16(f));
}
__device__ __forceinline__ short8v cvt8(float4 lo, float4 hi) {
  short8v r;
  r[0] = bfs(lo.x); r[1] = bfs(lo.y); r[2] = bfs(lo.z); r[3] = bfs(lo.w);
  r[4] = bfs(hi.x); r[5] = bfs(hi.y); r[6] = bfs(hi.z); r[7] = bfs(hi.w);
  return r;
}

// ---------------------------------------------------------------------------
// K0: pack fc_w (f32 [64][256]) into bf16 MFMA B-fragments.
// ---------------------------------------------------------------------------
__global__ __launch_bounds__(256) void k_wt(
    const float* __restrict__ fcw, short* __restrict__ wb)
{
  const int t = blockIdx.x * 256 + threadIdx.x;   // 0 .. 2047
  const int f = t >> 6;
  const int lane = t & 63;
  const int ks = f >> 2, cb = f & 3;
  const int col = cb * 16 + (lane & 15);
  const int kb = ks * 32 + (lane >> 4) * 8;
  short8v v;
  #pragma unroll
  for (int j = 0; j < 8; ++j) v[j] = bfs(fcw[col * FDIM + kb + j]);
  reinterpret_cast<short8v*>(wb)[t] = v;
}

// ---------------------------------------------------------------------------
// K1: MFMA GEMM z = x @ fc_w^T (bf16 in, f32 acc), fused s1/s2, z out bf16.
// C/D layout (verified): col = lane&15, row = (lane>>4)*4 + reg.
// ---------------------------------------------------------------------------
__global__ __launch_bounds__(256) void k_fcm(
    const float* __restrict__ x, const short* __restrict__ wb,
    const float* __restrict__ aw,
    unsigned short* __restrict__ zb, float* __restrict__ s1,
    float* __restrict__ s2, int N)
{
  __shared__ __align__(16) unsigned short zt[128 * 72];   // 18.4 KB transpose buf

  const int tid = threadIdx.x;
  const int lane = tid & 63;
  const int wave = tid >> 6;
  const int n0 = blockIdx.x * 128;
  const int rb = n0 + wave * 32;
  const int l4 = lane >> 4;      // k-group / row-group
  const int lm = lane & 15;      // A-row / B-col within tile

  f32x4 acc[2][4] = {};

  const int r0c = min(rb + lm, N - 1);
  const int r1c = min(rb + 16 + lm, N - 1);
  const float* xp0 = x + (size_t)r0c * FDIM + l4 * 8;
  const float* xp1 = x + (size_t)r1c * FDIM + l4 * 8;
  const short8v* wbv = reinterpret_cast<const short8v*>(wb);

  #pragma unroll
  for (int ks = 0; ks < 8; ++ks) {
    const float4 a0l = *reinterpret_cast<const float4*>(xp0 + ks * 32);
    const float4 a0h = *reinterpret_cast<const float4*>(xp0 + ks * 32 + 4);
    const float4 a1l = *reinterpret_cast<const float4*>(xp1 + ks * 32);
    const float4 a1h = *reinterpret_cast<const float4*>(xp1 + ks * 32 + 4);
    const short8v fa0 = cvt8(a0l, a0h);
    const short8v fa1 = cvt8(a1l, a1h);
    #pragma unroll
    for (int cb = 0; cb < 4; ++cb) {
      const short8v fb = wbv[(ks * 4 + cb) * 64 + lane];
      acc[0][cb] = __builtin_amdgcn_mfma_f32_16x16x32_bf16(fa0, fb, acc[0][cb], 0, 0, 0);
      acc[1][cb] = __builtin_amdgcn_mfma_f32_16x16x32_bf16(fa1, fb, acc[1][cb], 0, 0, 0);
    }
  }

  // fused s1/s2
  float aw1l[4], aw2l[4];
  #pragma unroll
  for (int cb = 0; cb < 4; ++cb) {
    aw1l[cb] = aw[cb * 16 + lm];
    aw2l[cb] = aw[HDIM + cb * 16 + lm];
  }
  #pragma unroll
  for (int mb = 0; mb < 2; ++mb) {
    const int rloc = rb + mb * 16 + l4 * 4;
    #pragma unroll
    for (int reg = 0; reg < 4; ++reg) {
      float t1 = 0.f, t2 = 0.f;
      #pragma unroll
      for (int cb = 0; cb < 4; ++cb) {
        t1 = fmaf(acc[mb][cb][reg], aw1l[cb], t1);
        t2 = fmaf(acc[mb][cb][reg], aw2l[cb], t2);
      }
      #pragma unroll
      for (int off = 1; off < 16; off <<= 1) {
        t1 += __shfl_xor(t1, off, 64);
        t2 += __shfl_xor(t2, off, 64);
      }
      if (lm == reg && rloc + reg < N) {
        s1[rloc + reg] = t1;
        s2[rloc + reg] = t2;
      }
    }
  }

  // z -> bf16 via LDS transpose, then coalesced stores (64B per thread)
  #pragma unroll
  for (int mb = 0; mb < 2; ++mb)
    #pragma unroll
    for (int cb = 0; cb < 4; ++cb)
      #pragma unroll
      for (int reg = 0; reg < 4; ++reg) {
        const int rl = wave * 32 + mb * 16 + l4 * 4 + reg;
        zt[rl * 72 + cb * 16 + lm] =
            (unsigned short)__builtin_bit_cast(unsigned short,
                __float2bfloat16(acc[mb][cb][reg]));
      }
  __syncthreads();
  const int row = tid >> 1, hf = tid & 1;   // 32 u16 = 64 B = 4 x uint4 each
  const int n = n0 + row;
  if (n < N) {
    const uint4* s = reinterpret_cast<const uint4*>(&zt[row * 72 + hf * 32]);
    uint4 v0 = s[0], v1 = s[1], v2 = s[2], v3 = s[3];
    uint4* d = reinterpret_cast<uint4*>(zb + (size_t)n * HDIM + hf * 32);
    d[0] = v0; d[1] = v1; d[2] = v2; d[3] = v3;
  }
}

// ---------------------------------------------------------------------------
// K2: LDS-privatized histogram. One block per (1<<chunkLg)-edge chunk.
// ---------------------------------------------------------------------------
__global__ __launch_bounds__(1024) void k_histL(
    const int* __restrict__ src, unsigned int* __restrict__ hist,
    unsigned short* __restrict__ lrank, int E, int nCol, int chunkLg)
{
  __shared__ unsigned int lh[LH_CAP];     // 100 KB
  const int tid = threadIdx.x;
  for (int i = tid; i < nCol; i += 1024) lh[i] = 0;
  __syncthreads();
  const int e0 = blockIdx.x << chunkLg;
  const int e1 = min(e0 + (1 << chunkLg), E);
  for (int e = e0 + tid; e < e1; e += 1024) {
    const int s = src[e];
    const int sh = (s & 1) * 16;
    const unsigned int old = atomicAdd(&lh[s >> 1], 1u << sh);
    lrank[e] = (unsigned short)((old >> sh) & 0xffffu);
  }
  __syncthreads();
  unsigned int* hrow = hist + (size_t)blockIdx.x * nCol;
  for (int i = tid; i < nCol; i += 1024) hrow[i] = lh[i];
}

// ---------------------------------------------------------------------------
// K2b: column scan over blocks (in-place) + total counts cnt[n].
// ---------------------------------------------------------------------------
__global__ __launch_bounds__(256) void k_colscan(
    unsigned int* __restrict__ hist, int* __restrict__ cnt,
    int nCol, int B, int N)
{
  const int c = blockIdx.x * 256 + threadIdx.x;
  if (c >= nCol) return;
  unsigned int s0 = 0, s1 = 0;
  for (int b = 0; b < B; ++b) {
    unsigned int* p = hist + (size_t)b * nCol + c;
    const unsigned int v = *p;
    *p = s0 | (s1 << 16);
    s0 += v & 0xffffu;
    s1 += v >> 16;
  }
  const int n0 = 2 * c;
  if (n0 < N) cnt[n0] = (int)s0;
  if (n0 + 1 < N) cnt[n0 + 1] = (int)s1;
}

// ---------------------------------------------------------------------------
// K3a: per-block exclusive scan (1024/block) + block sums
// ---------------------------------------------------------------------------
__global__ __launch_bounds__(1024) void k_scan1(
    const int* __restrict__ cnt, int* __restrict__ rowptr,
    int* __restrict__ bsum, int N)
{
  __shared__ int wsum[16];
  const int i = blockIdx.x * 1024 + threadIdx.x;
  const int lane = threadIdx.x & 63;
  const int wave = threadIdx.x >> 6;
  const int v = (i < N) ? cnt[i] : 0;
  int s = v;
  #pragma unroll
  for (int off = 1; off < 64; off <<= 1) {
    int t = __shfl_up(s, off, 64);
    if (lane >= off) s += t;
  }
  if (lane == 63) wsum[wave] = s;
  __syncthreads();
  if (threadIdx.x < 16) {
    int w = wsum[threadIdx.x];
    #pragma unroll
    for (int off = 1; off < 16; off <<= 1) {
      int t = __shfl_up(w, off, 64);
      if (threadIdx.x >= off) w += t;
    }
    wsum[threadIdx.x] = w;   // inclusive across waves
  }
  __syncthreads();
  const int base = (wave > 0) ? wsum[wave - 1] : 0;
  if (i < N) rowptr[i] = base + s - v;      // block-local exclusive
  if (threadIdx.x == 0) bsum[blockIdx.x] = wsum[15];
}

// ---------------------------------------------------------------------------
// K3b: single-block exclusive scan of block sums (B <= 1024)
// ---------------------------------------------------------------------------
__global__ __launch_bounds__(1024) void k_scan2(int* __restrict__ bsum, int B)
{
  __shared__ int part[1024];
  const int t = threadIdx.x;
  const int v = (t < B) ? bsum[t] : 0;
  part[t] = v;
  __syncthreads();
  for (int off = 1; off < 1024; off <<= 1) {
    int u = (t >= off) ? part[t - off] : 0;
    __syncthreads();
    part[t] += u;
    __syncthreads();
  }
  if (t < B) bsum[t] = part[t] - v;   // exclusive
}

// ---------------------------------------------------------------------------
// K3c: add block offsets; set rowptr[N] = E
// ---------------------------------------------------------------------------
__global__ __launch_bounds__(1024) void k_scan3(
    int* __restrict__ rowptr, const int* __restrict__ bsum, int N, int E)
{
  const int i = blockIdx.x * 1024 + threadIdx.x;
  if (i < N) rowptr[i] += bsum[blockIdx.x];
  if (i == 0) rowptr[N] = E;
}

// ---------------------------------------------------------------------------
// K4: atomic-free CSR placement:
// pos = rowptr[src] + colbase[e>>chunkLg][src] + lrank[e]
// ---------------------------------------------------------------------------
__global__ __launch_bounds__(256) void k_place(
    const int* __restrict__ src, const int* __restrict__ dst,
    const int* __restrict__ rowptr, const unsigned int* __restrict__ colbase,
    const unsigned short* __restrict__ lrank,
    unsigned short* __restrict__ csr_dst, int E, int nCol, int chunkLg)
{
  int e = blockIdx.x * 256 + threadIdx.x;
  if (e >= E) return;
  const int s = src[e];
  const unsigned int cb = colbase[(size_t)(e >> chunkLg) * nCol + (s >> 1)];
  const int base = (int)((cb >> ((s & 1) * 16)) & 0xffffu);
  csr_dst[rowptr[s] + base + (int)lrank[e]] = (unsigned short)dst[e];
}

// ---------------------------------------------------------------------------
// K5: node-centric accumulate; wave/node; 2 edges per gather.
// h/dl broadcast through LDS (no convergent ops in pair loop) so the loop
// can be manually batched 4x -> 4 independent 256B gathers in flight.
// ---------------------------------------------------------------------------
__global__ __launch_bounds__(256) void k_node(
    const unsigned short* __restrict__ csr_dst, const int* __restrict__ rowptr,
    const float* __restrict__ s1, const float* __restrict__ s2,
    const float* __restrict__ ab, const unsigned short* __restrict__ zb,
    float* __restrict__ out, float* __restrict__ rinv, int N)
{
  __shared__ float hbuf[4][64];
  __shared__ int   dbuf[4][64];

  const int wave = threadIdx.x >> 6;
  const int node = blockIdx.x * 4 + wave;
  const int lane = threadIdx.x & 63;
  if (node >= N) return;
  const int r0 = rowptr[node];
  const int r1 = rowptr[node + 1];
  if (r1 == r0) {            // degree-0: reference yields zeros
    out[(size_t)node * HDIM + lane] = 0.f;
    if (lane == 0) rinv[node] = 0.f;
    return;
  }
  const float s1n = s1[node];
  const float b = ab[0];
  const int half = lane >> 5;
  const int fp = (lane & 31) << 1;   // feature pair base
  float ax = 0.f, ay = 0.f, hs = 0.f;
  float* hb = hbuf[wave];
  int*   db = dbuf[wave];

  for (int base = r0; base < r1; base += 64) {
    const int j = base + lane;
    float h = 0.f;
    int dl = 0;
    if (j < r1) {
      dl = (int)csr_dst[j];                  // coalesced u16
      float v = s1n + s2[dl] + b;            // gathered 4B (L2-resident)
      v = v > 0.f ? v : LEAKY * v;
      h = __expf(v);
    }
    hs += h;
    hb[lane] = h;                            // wave-private LDS, no barrier
    db[lane] = dl;
    const int cnt = min(64, r1 - base);
    const int pairs = (cnt + 1) >> 1;
    int t = 0;
    for (; t + 4 <= pairs; t += 4) {
      const int i0 = 2 * t + half;
      const float h0 = hb[i0],     h1 = hb[i0 + 2];
      const float h2 = hb[i0 + 4], h3 = hb[i0 + 6];
      const int   d0 = db[i0],     d1 = db[i0 + 2];
      const int   d2 = db[i0 + 4], d3 = db[i0 + 6];
      const unsigned int w0 = *reinterpret_cast<const unsigned int*>(zb + (size_t)d0 * HDIM + fp);
      const unsigned int w1 = *reinterpret_cast<const unsigned int*>(zb + (size_t)d1 * HDIM + fp);
      const unsigned int w2 = *reinterpret_cast<const unsigned int*>(zb + (size_t)d2 * HDIM + fp);
      const unsigned int w3 = *reinterpret_cast<const unsigned int*>(zb + (size_t)d3 * HDIM + fp);
      ax = fmaf(h0, __uint_as_float(w0 << 16), ax);
      ay = fmaf(h0, __uint_as_float(w0 & 0xffff0000u), ay);
      ax = fmaf(h1, __uint_as_float(w1 << 16), ax);
      ay = fmaf(h1, __uint_as_float(w1 & 0xffff0000u), ay);
      ax = fmaf(h2, __uint_as_float(w2 << 16), ax);
      ay = fmaf(h2, __uint_as_float(w2 & 0xffff0000u), ay);
      ax = fmaf(h3, __uint_as_float(w3 << 16), ax);
      ay = fmaf(h3, __uint_as_float(w3 & 0xffff0000u), ay);
    }
    for (; t < pairs; ++t) {
      const int i0 = 2 * t + half;
      const float hB = hb[i0];
      const int   dB = db[i0];
      const unsigned int w = *reinterpret_cast<const unsigned int*>(zb + (size_t)dB * HDIM + fp);
      ax = fmaf(hB, __uint_as_float(w << 16), ax);
      ay = fmaf(hB, __uint_as_float(w & 0xffff0000u), ay);
    }
  }
  #pragma unroll
  for (int off = 32; off > 0; off >>= 1) hs += __shfl_xor(hs, off, 64);
  // combine even/odd halves (same feature pair lives at lane^32)
  ax += __shfl_xor(ax, 32, 64);
  ay += __shfl_xor(ay, 32, 64);
  const float inv = 1.0f / hs;
  if (lane < 32) {
    float2 o = {ax * inv, ay * inv};
    *reinterpret_cast<float2*>(out + (size_t)node * HDIM + fp) = o;
    if (lane == 0) rinv[node] = inv;
  }
}

// ---------------------------------------------------------------------------
// K6: alpha in edge order (coalesced writes)
// ---------------------------------------------------------------------------
__global__ __launch_bounds__(256) void k_alpha(
    const int* __restrict__ src, const int* __restrict__ dst,
    const float* __restrict__ s1, const float* __restrict__ s2,
    const float* __restrict__ ab, const float* __restrict__ rinv,
    float* __restrict__ alpha, int E)
{
  int e = blockIdx.x * blockDim.x + threadIdx.x;
  if (e >= E) return;
  const int s = src[e];
  float v = s1[s] + s2[dst[e]] + ab[0];
  v = v > 0.f ? v : LEAKY * v;
  alpha[e] = __expf(v) * rinv[s];
}

extern "C" void kernel_launch(void* const* d_in, const int* in_sizes, int n_in,
                              void* d_out, int out_size, void* d_ws, size_t ws_size,
                              hipStream_t stream) {
  const int E  = in_sizes[1] / 2;
  const int H2 = in_sizes[3];            // 2*H = 128
  const int Hh = H2 / 2;                 // 64
  const int Ff = in_sizes[2] / Hh;       // 256
  const int N  = in_sizes[0] / Ff;       // 50000

  const float* x   = (const float*)d_in[0];
  const int*   ei  = (const int*)d_in[1];
  const float* fcw = (const float*)d_in[2];
  const float* aw  = (const float*)d_in[3];
  const float* ab  = (const float*)d_in[4];
  const int* src = ei;
  const int* dst = ei + E;

  float* out   = (float*)d_out;
  float* alpha = out + (size_t)N * HDIM;

  const int nCol = (N + 1) / 2;                       // packed u16-pair columns

  // workspace layout:
  // zb u16[N*64] | s1 f32[N] | s2 f32[N] | rinv f32[N] | wb s16[16384]
  // | cnt i32[N] | rowptr i32[N+1] | bsum i32[1024] | lrank u16[E]
  // | csr_dst u16[E] | hist u32[nbH*nCol]
  unsigned short* zb = (unsigned short*)d_ws;
  float* s1   = (float*)(zb + (size_t)N * HDIM);
  float* s2   = s1 + N;
  float* rinv = s2 + N;
  short* wb   = (short*)(rinv + N);
  int* cnt    = (int*)(wb + 8 * 4 * 64 * 8);
  int* rowptr = cnt + N;
  int* bsum   = rowptr + (N + 1);
  unsigned short* lrank   = (unsigned short*)(bsum + 1024);
  unsigned short* csr_dst = lrank + E;
  unsigned int* hist = (unsigned int*)(csr_dst + ((E + 1) & ~1));

  // 32768-edge chunks (49 rows @ E=1.6M); grow chunk if hist wouldn't fit.
  const size_t fixed_bytes = (size_t)((char*)hist - (char*)d_ws);
  int chunkLg = 15;
  while (chunkLg < 22) {
    const size_t nbH_t = ((size_t)E + ((size_t)1 << chunkLg) - 1) >> chunkLg;
    if (fixed_bytes + nbH_t * (size_t)nCol * 4 <= ws_size) break;
    ++chunkLg;
  }
  const int nbH = (int)(((size_t)E + ((size_t)1 << chunkLg) - 1) >> chunkLg);

  k_wt<<<8, 256, 0, stream>>>(fcw, wb);
  k_fcm<<<(N + 127) / 128, 256, 0, stream>>>(x, wb, aw, zb, s1, s2, N);

  k_histL<<<nbH, 1024, 0, stream>>>(src, hist, lrank, E, nCol, chunkLg);
  k_colscan<<<(nCol + 255) / 256, 256, 0, stream>>>(hist, cnt, nCol, nbH, N);

  const int nb1 = (N + 1023) / 1024;
  k_scan1<<<nb1, 1024, 0, stream>>>(cnt, rowptr, bsum, N);
  k_scan2<<<1, 1024, 0, stream>>>(bsum, nb1);
  k_scan3<<<nb1, 1024, 0, stream>>>(rowptr, bsum, N, E);

  const int eb = (E + 255) / 256;
  k_place<<<eb, 256, 0, stream>>>(src, dst, rowptr, hist, lrank, csr_dst,
                                  E, nCol, chunkLg);

  k_node<<<(N + 3) / 4, 256, 0, stream>>>(
      csr_dst, rowptr, s1, s2, ab, zb, out, rinv, N);

  k_alpha<<<eb, 256, 0, stream>>>(src, dst, s1, s2, ab, rinv, alpha, E);
}